// Round 1
// 202.480 us; speedup vs baseline: 1.0091x; 1.0091x over previous
//
#include <hip/hip_runtime.h>
#include <stdint.h>

#define NN3 262144
#define NN2 65536
#define NN1 16384

typedef __attribute__((ext_vector_type(8))) __bf16 bf16x8;
typedef __attribute__((ext_vector_type(4))) float floatx4;

static __device__ __forceinline__ float bf2f(unsigned short u) {
    union { unsigned int i; float f; } v; v.i = ((unsigned int)u) << 16; return v.f;
}
static __device__ __forceinline__ unsigned short f2bf(float f) {
    union { float f; unsigned int i; } v; v.f = f;
    unsigned int x = v.i;
    return (unsigned short)((x + 0x7fffu + ((x >> 16) & 1u)) >> 16);
}
static __device__ __forceinline__ bf16x8 zero_bf16x8() {
    bf16x8 z;
#pragma unroll
    for (int i = 0; i < 8; ++i) z[i] = (__bf16)0.0f;
    return z;
}

// ---------------- swizzled weight prep ----------------
// Lays B out in MFMA-fragment order so the conv's B-load is ONE fully-coalesced
// 1KB wave load per (n,kt) instead of a 16-cache-line scatter:
//   out[((n*KT + kt)*64 + lane)*8 + e] = w[(n*16 + m)*K + kt*32 + quad*8 + e]
// with lane = quad*16 + m.  k >= K zero-padded (lets conv drop the B guard).
template <int CIN, int COUT>
static __device__ __forceinline__ void prep_swz(const float* __restrict__ w,
                                                unsigned short* __restrict__ out, int g) {
    constexpr int K = 9 * CIN, KT = (K + 31) / 32;
    int n = g / (KT * 512);
    int r = g - n * (KT * 512);
    int kt = r >> 9;
    int q = r & 511;
    int lane = q >> 3, e = q & 7;
    int m = lane & 15, quad = lane >> 4;
    int k = kt * 32 + quad * 8 + e;
    float v = (k < K) ? w[(n * 16 + m) * K + k] : 0.0f;
    out[g] = f2bf(v);
}

// ---------------- enc1 + pool1 fused, with swizzled weight prep folded in ----------------
__global__ __launch_bounds__(256) void enc1pool_kernel(
    const float* __restrict__ feat, const int* __restrict__ neigh,
    const float* __restrict__ w, const float* __restrict__ b,
    unsigned short* __restrict__ x7p,
    const float* __restrict__ w_enc2, const float* __restrict__ w_enc3,
    const float* __restrict__ w_dec1, const float* __restrict__ w_dec2,
    unsigned short* __restrict__ wb_enc2, unsigned short* __restrict__ wb_enc3,
    unsigned short* __restrict__ wb_dec1, unsigned short* __restrict__ wb_dec2)
{
    // folded swizzled weight prep: 46592 elements over the first 182 blocks
    {
        int g = blockIdx.x * 256 + threadIdx.x;
        if (g < 5120) prep_swz<16, 32>(w_enc2, wb_enc2, g);          // NT=2 KT=5
        else {
            g -= 5120;
            if (g < 18432) prep_swz<32, 64>(w_enc3, wb_enc3, g);     // NT=4 KT=9
            else {
                g -= 18432;
                if (g < 18432) prep_swz<64, 32>(w_dec1, wb_dec1, g); // NT=2 KT=18
                else { g -= 18432; if (g < 4608) prep_swz<32, 16>(w_dec2, wb_dec2, g); } // NT=1 KT=9
            }
        }
    }
    __shared__ float ws[144];
    __shared__ float bs[16];
    __shared__ int nsh[2304];
    int t = threadIdx.x;
    if (t < 144) ws[t] = w[t];
    if (t < 16)  bs[t] = b[t];
    int base = blockIdx.x * 256;
    for (int e = t; e < 2304; e += 256)
        nsh[e] = __builtin_nontemporal_load(&neigh[(size_t)base * 9 + e]);
    __syncthreads();
    float f[9];
#pragma unroll
    for (int k = 0; k < 9; ++k) { int j = nsh[t * 9 + k]; f[k] = (j < 0) ? 0.0f : feat[j]; }
    float v[16];
#pragma unroll
    for (int co = 0; co < 16; ++co) {
        float a = bs[co];
#pragma unroll
        for (int k = 0; k < 9; ++k) a += f[k] * ws[co * 9 + k];
        v[co] = fmaxf(a, 0.0f);
    }
#pragma unroll
    for (int co = 0; co < 16; ++co) {
        v[co] = fmaxf(v[co], __shfl_xor(v[co], 1));
        v[co] = fmaxf(v[co], __shfl_xor(v[co], 2));
    }
    if ((t & 3) == 0) {
        unsigned int ov[8];
#pragma unroll
        for (int h = 0; h < 8; ++h)
            ov[h] = (unsigned int)f2bf(v[2 * h]) | (((unsigned int)f2bf(v[2 * h + 1])) << 16);
        uint4* dst = (uint4*)(x7p + (size_t)((base + t) >> 2) * 16);
        dst[0] = make_uint4(ov[0], ov[1], ov[2], ov[3]);
        dst[1] = make_uint4(ov[4], ov[5], ov[6], ov[7]);
    }
}

// ---------------- generic MFMA conv ----------------
// TILES: row-tiles of 16 per wave (ILP: TILES independent A-gathers in flight).
// WN:    waves splitting COUT (TLP: grid grows xWN; A-gathers duplicated xWN but
//        we are gather-latency-bound, so more resident waves > fewer instrs).
// SHIFT: gather src[neigh>>2] (fused unpool). POOL: 4:1 row-max epilogue.
// B is pre-swizzled (see prep_swz): one coalesced 16B/lane load per (n,kt).
// A-gathers are software-pipelined one kt ahead of the MFMAs consuming them.
template <int CIN, int COUT, bool SHIFT, bool POOL, int TILES, int WN>
__global__ __launch_bounds__(256) void conv_mfma(
    const unsigned short* __restrict__ src, const int* __restrict__ neigh,
    const unsigned short* __restrict__ wb, const float* __restrict__ bias,
    unsigned short* __restrict__ dst)
{
    constexpr int K   = 9 * CIN;
    constexpr int KT  = (K + 31) / 32;
    constexpr int NT  = COUT / 16;
    constexpr int WM  = 4 / WN;      // wave-groups along rows
    constexpr int NTW = NT / WN;     // couts-of-16 per wave
    constexpr int ROWS = WM * TILES * 16;
    __shared__ int nsh[ROWS * 9];
    int t = threadIdx.x;
    int rowbase = blockIdx.x * ROWS;
    for (int e = t; e < ROWS * 9; e += 256) {
        int j = __builtin_nontemporal_load(&neigh[(size_t)rowbase * 9 + e]);
        if (SHIFT) j = (j < 0) ? -1 : (j >> 2);
        nsh[e] = j;
    }
    __syncthreads();
    int lane = t & 63;
    int wave = t >> 6;
    int wm   = wave / WN;
    int wn   = wave - wm * WN;
    int m    = lane & 15;
    int quad = lane >> 4;
    int rbase9[TILES];
#pragma unroll
    for (int tl = 0; tl < TILES; ++tl)
        rbase9[tl] = ((wm * TILES + tl) * 16 + m) * 9;

    floatx4 acc[TILES][NTW];
#pragma unroll
    for (int tl = 0; tl < TILES; ++tl)
#pragma unroll
        for (int n = 0; n < NTW; ++n) acc[tl][n] = (floatx4){0.f, 0.f, 0.f, 0.f};

    auto gatherA = [&](int kt, bf16x8 (&dstA)[TILES]) {
        int k0 = kt * 32 + quad * 8;
#pragma unroll
        for (int tl = 0; tl < TILES; ++tl) {
            dstA[tl] = zero_bf16x8();
            if (k0 < K) {
                int j = nsh[rbase9[tl] + k0 / CIN];
                if (j >= 0) dstA[tl] = *(const bf16x8*)(src + (size_t)j * CIN + (k0 % CIN));
            }
        }
    };

    bf16x8 aC[TILES], aP[TILES];
    gatherA(0, aC);
#pragma unroll
    for (int kt = 0; kt < KT; ++kt) {
        if (kt + 1 < KT) gatherA(kt + 1, aP);   // issue next gathers before MFMAs
#pragma unroll
        for (int n = 0; n < NTW; ++n) {
            int ng = wn * NTW + n;              // global cout-group
            bf16x8 bfrag = *(const bf16x8*)(wb + ((size_t)(ng * KT + kt) * 64 + lane) * 8);
#pragma unroll
            for (int tl = 0; tl < TILES; ++tl)
                acc[tl][n] = __builtin_amdgcn_mfma_f32_16x16x32_bf16(aC[tl], bfrag, acc[tl][n], 0, 0, 0);
        }
#pragma unroll
        for (int tl = 0; tl < TILES; ++tl) aC[tl] = aP[tl];
    }

#pragma unroll
    for (int tl = 0; tl < TILES; ++tl) {
        int rg = wm * TILES + tl;
        if (POOL) {
            int p = (rowbase >> 2) + rg * 4 + quad;
#pragma unroll
            for (int n = 0; n < NTW; ++n) {
                int cout = (wn * NTW + n) * 16 + m;
                float vm = fmaxf(fmaxf(acc[tl][n][0], acc[tl][n][1]), fmaxf(acc[tl][n][2], acc[tl][n][3]));
                float v  = fmaxf(vm + bias[cout], 0.0f);
                dst[(size_t)p * COUT + cout] = f2bf(v);
            }
        } else {
            int grow = rowbase + rg * 16 + quad * 4;
#pragma unroll
            for (int n = 0; n < NTW; ++n) {
                int cout = (wn * NTW + n) * 16 + m;
                float bv = bias[cout];
#pragma unroll
                for (int r = 0; r < 4; ++r) {
                    float v = fmaxf(acc[tl][n][r] + bv, 0.0f);
                    dst[(size_t)(grow + r) * COUT + cout] = f2bf(v);
                }
            }
        }
    }
}

// ---------------- head: Cin=16 bf16 -> 1 fp32, no relu; 2 rows per thread ----------------
static __device__ __forceinline__ float dot2(unsigned int u, const float* w) {
    return bf2f((unsigned short)(u & 0xffffu)) * w[0] + bf2f((unsigned short)(u >> 16)) * w[1];
}
__global__ __launch_bounds__(256) void head_kernel(
    const unsigned short* __restrict__ x, const int* __restrict__ neigh,
    const float* __restrict__ w, const float* __restrict__ b, float* __restrict__ out)
{
    __shared__ float ws[144];
    __shared__ int nsh[4608];
    int t = threadIdx.x;
    if (t < 144) ws[t] = w[t];
    int base = blockIdx.x * 512;
    for (int e = t; e < 4608; e += 256)
        nsh[e] = __builtin_nontemporal_load(&neigh[(size_t)base * 9 + e]);
    __syncthreads();
    float acc0 = b[0], acc1 = b[0];
#pragma unroll
    for (int k = 0; k < 9; ++k) {
        int j0 = nsh[t * 9 + k];
        int j1 = nsh[(256 + t) * 9 + k];
        const float* wp = &ws[k * 16];
        if (j0 >= 0) {
            const uint4* r = (const uint4*)(x + (size_t)j0 * 16);
            uint4 r0 = r[0], r1 = r[1];
            acc0 += dot2(r0.x, wp)     + dot2(r0.y, wp + 2)  + dot2(r0.z, wp + 4)  + dot2(r0.w, wp + 6);
            acc0 += dot2(r1.x, wp + 8) + dot2(r1.y, wp + 10) + dot2(r1.z, wp + 12) + dot2(r1.w, wp + 14);
        }
        if (j1 >= 0) {
            const uint4* r = (const uint4*)(x + (size_t)j1 * 16);
            uint4 r0 = r[0], r1 = r[1];
            acc1 += dot2(r0.x, wp)     + dot2(r0.y, wp + 2)  + dot2(r0.z, wp + 4)  + dot2(r0.w, wp + 6);
            acc1 += dot2(r1.x, wp + 8) + dot2(r1.y, wp + 10) + dot2(r1.z, wp + 12) + dot2(r1.w, wp + 14);
        }
    }
    __builtin_nontemporal_store(acc0, &out[base + t]);
    __builtin_nontemporal_store(acc1, &out[base + 256 + t]);
}

extern "C" void kernel_launch(void* const* d_in, const int* in_sizes, int n_in,
                              void* d_out, int out_size, void* d_ws, size_t ws_size,
                              hipStream_t stream) {
    const float* features = (const float*)d_in[0];
    const int* neighs3 = (const int*)d_in[4];
    const int* neighs2 = (const int*)d_in[5];
    const int* neighs1 = (const int*)d_in[6];
    const float* w_enc1 = (const float*)d_in[7];
    const float* b_enc1 = (const float*)d_in[8];
    const float* w_enc2 = (const float*)d_in[9];
    const float* b_enc2 = (const float*)d_in[10];
    const float* w_enc3 = (const float*)d_in[11];
    const float* b_enc3 = (const float*)d_in[12];
    const float* w_dec1 = (const float*)d_in[13];
    const float* b_dec1 = (const float*)d_in[14];
    const float* w_dec2 = (const float*)d_in[15];
    const float* b_dec2 = (const float*)d_in[16];
    const float* w_head = (const float*)d_in[17];
    const float* b_head = (const float*)d_in[18];

    char* ws = (char*)d_ws;
    size_t off = 0;
    unsigned short* wb_enc2 = (unsigned short*)(ws + off); off += 5120 * 2;    // NT*KT*512, kt-padded
    unsigned short* wb_enc3 = (unsigned short*)(ws + off); off += 18432 * 2;
    unsigned short* wb_dec1 = (unsigned short*)(ws + off); off += 18432 * 2;
    unsigned short* wb_dec2 = (unsigned short*)(ws + off); off += 4608 * 2;
    unsigned short* x7p   = (unsigned short*)(ws + off); off += (size_t)NN2 * 16 * 2;
    unsigned short* x6p   = (unsigned short*)(ws + off); off += (size_t)NN1 * 32 * 2;
    unsigned short* x6    = (unsigned short*)(ws + off); off += (size_t)NN1 * 64 * 2;
    unsigned short* x7dec = (unsigned short*)(ws + off); off += (size_t)NN2 * 32 * 2;
    unsigned short* x8dec = (unsigned short*)(ws + off); off += (size_t)NN3 * 16 * 2;

    // All conv grids = 1024 blocks = 4 blocks/CU = 16 waves/CU (was 256..1024).
    // 1. enc1 + pool1 (+ folded swizzled weight prep): features -> x7p [N2,16]
    enc1pool_kernel<<<NN3 / 256, 256, 0, stream>>>(features, neighs3, w_enc1, b_enc1, x7p,
                                                   w_enc2, w_enc3, w_dec1, w_dec2,
                                                   wb_enc2, wb_enc3, wb_dec1, wb_dec2);
    // 2. enc2 + pool2: x7p -> x6p [N1,32]   (TILES=2, WN=2: 64 rows/block)
    conv_mfma<16, 32, false, true, 2, 2><<<NN2 / 64, 256, 0, stream>>>(x7p, neighs2, wb_enc2, b_enc2, x6p);
    // 3. enc3: x6p -> x6 [N1,64]            (TILES=1, WN=4: 16 rows/block; was 1 blk/CU)
    conv_mfma<32, 64, false, false, 1, 4><<<NN1 / 16, 256, 0, stream>>>(x6p, neighs1, wb_enc3, b_enc3, x6);
    // 4. dec1 (fused unpool): x6 -> x7dec [N2,32]   (TILES=2, WN=2)
    conv_mfma<64, 32, true, false, 2, 2><<<NN2 / 64, 256, 0, stream>>>(x6, neighs2, wb_dec1, b_dec1, x7dec);
    // 5. dec2 (fused unpool): x7dec -> x8dec [N3,16]  (TILES=4, WN=1, NT=1 can't split)
    conv_mfma<32, 16, true, false, 4, 1><<<NN3 / 256, 256, 0, stream>>>(x7dec, neighs3, wb_dec2, b_dec2, x8dec);
    // 6. head: x8dec -> out [N3,1]f32       (2 rows/thread)
    head_kernel<<<NN3 / 512, 256, 0, stream>>>(x8dec, neighs3, w_head, b_head, (float*)d_out);
}